// Round 1
// baseline (580.604 us; speedup 1.0000x reference)
//
#include <hip/hip_runtime.h>

#define NN     100000
#define DEG    16
#define IN_F   128
#define OUT_F  32
#define KK     4
#define JDIM   (KK * OUT_F)   // 128

// ---------------------------------------------------------------------------
// Kernel A: node_feat[n][j] = sum_i feat[n][i] * fc_w[j][i]   (j = k*32+f)
// Tile: 16 nodes x 128 j per block (256 threads). feat tile staged in LDS,
// fc_w streamed via float4 (64 KB total, L1/L2 resident across blocks).
// Each thread: 2 nodes x 4 consecutive j.
// ---------------------------------------------------------------------------
__global__ __launch_bounds__(256) void gmm_fc_gemm(
    const float* __restrict__ feat, const float* __restrict__ fc_w,
    float* __restrict__ nf)
{
  __shared__ float s_feat[16][IN_F];   // 8 KB
  const int tid = threadIdx.x;
  const int node0 = blockIdx.x * 16;

  // stage 16x128 = 2048 floats = 512 float4 (2 per thread), coalesced
  const float4* fsrc = (const float4*)(feat + (size_t)node0 * IN_F);
  float4* fdst = (float4*)&s_feat[0][0];
  fdst[tid]       = fsrc[tid];
  fdst[tid + 256] = fsrc[tid + 256];
  __syncthreads();

  const int jq = (tid & 31) * 4;   // j0..j0+3
  const int np = tid >> 5;         // 0..7 -> nodes 2np, 2np+1
  const int n0 = np * 2, n1 = n0 + 1;

  float acc0[4] = {0.f, 0.f, 0.f, 0.f};
  float acc1[4] = {0.f, 0.f, 0.f, 0.f};

  for (int i0 = 0; i0 < IN_F; i0 += 4) {
    const float4 f0 = *(const float4*)&s_feat[n0][i0];
    const float4 f1 = *(const float4*)&s_feat[n1][i0];
#pragma unroll
    for (int jj = 0; jj < 4; ++jj) {
      const float4 w = *(const float4*)&fc_w[(size_t)(jq + jj) * IN_F + i0];
      acc0[jj] += f0.x * w.x + f0.y * w.y + f0.z * w.z + f0.w * w.w;
      acc1[jj] += f1.x * w.x + f1.y * w.y + f1.z * w.z + f1.w * w.w;
    }
  }

  float4 a0 = {acc0[0], acc0[1], acc0[2], acc0[3]};
  float4 a1 = {acc1[0], acc1[1], acc1[2], acc1[3]};
  *(float4*)&nf[(size_t)(node0 + n0) * JDIM + jq] = a0;
  *(float4*)&nf[(size_t)(node0 + n1) * JDIM + jq] = a1;
}

// ---------------------------------------------------------------------------
// Kernel B: per dst node i (owns edges rowptr[i]..rowptr[i]+15):
//   out[i][f] = bias[f] + sum_e sum_k w[e,k] * nf[src_e][k*32+f]
// Block = 256 threads = 32 nodes x 8 feature-quads. 512 edges staged:
// src ids + gaussian weights w[e][0..3] computed once into LDS.
// Gathers: float4, 8 lanes x 16B = 128B coalesced per (src,k).
// ---------------------------------------------------------------------------
__global__ __launch_bounds__(256) void gmm_edge_scatter(
    const int* __restrict__ rowptr, const int* __restrict__ colind,
    const int* __restrict__ permute, const float* __restrict__ pseudo,
    const float* __restrict__ mu, const float* __restrict__ inv_sigma,
    const float* __restrict__ bias, const float* __restrict__ nf,
    float* __restrict__ out)
{
  __shared__ int   s_src[512];      // 2 KB
  __shared__ float s_w[512][4];     // 8 KB

  const int tid = threadIdx.x;
  const int node0 = blockIdx.x * 32;

  // gaussian params to registers (uniform scalar loads)
  float mx[KK], my[KK], sx[KK], sy[KK];
#pragma unroll
  for (int k = 0; k < KK; ++k) {
    mx[k] = mu[k * 2 + 0];
    my[k] = mu[k * 2 + 1];
    sx[k] = inv_sigma[k * 2 + 0];
    sy[k] = inv_sigma[k * 2 + 1];
  }

  // stage 512 edges, 2 per thread
#pragma unroll
  for (int r = 0; r < 2; ++r) {
    const int t  = tid + r * 256;   // 0..511
    const int nl = t >> 4;          // local node 0..31
    const int el = t & 15;
    const int e  = rowptr[node0 + nl] + el;
    const int src = colind[e];
    const int pe  = permute[e];
    const float px = pseudo[(size_t)pe * 2 + 0];
    const float py = pseudo[(size_t)pe * 2 + 1];
    s_src[t] = src;
#pragma unroll
    for (int k = 0; k < KK; ++k) {
      const float dx = (px - mx[k]) * sx[k];
      const float dy = (py - my[k]) * sy[k];
      s_w[t][k] = __expf(-0.5f * (dx * dx + dy * dy));
    }
  }
  __syncthreads();

  const int nl = tid >> 3;   // 0..31 local node
  const int f4 = tid & 7;    // feature quad: features 4*f4 .. 4*f4+3

  float4 acc = *(const float4*)&bias[f4 * 4];
  const int tbase = nl * 16;

#pragma unroll 4
  for (int e = 0; e < DEG; ++e) {
    const int src = s_src[tbase + e];
    const float4 w = *(const float4*)&s_w[tbase + e][0];
    const float4* p = (const float4*)nf + (size_t)src * (JDIM / 4) + f4;
    const float4 v0 = p[0];    // k=0
    const float4 v1 = p[8];    // k=1
    const float4 v2 = p[16];   // k=2
    const float4 v3 = p[24];   // k=3
    acc.x += w.x * v0.x + w.y * v1.x + w.z * v2.x + w.w * v3.x;
    acc.y += w.x * v0.y + w.y * v1.y + w.z * v2.y + w.w * v3.y;
    acc.z += w.x * v0.z + w.y * v1.z + w.z * v2.z + w.w * v3.z;
    acc.w += w.x * v0.w + w.y * v1.w + w.z * v2.w + w.w * v3.w;
  }

  *(float4*)&out[(size_t)(node0 + nl) * OUT_F + f4 * 4] = acc;
}

extern "C" void kernel_launch(void* const* d_in, const int* in_sizes, int n_in,
                              void* d_out, int out_size, void* d_ws, size_t ws_size,
                              hipStream_t stream) {
  const int*   rowptr    = (const int*)d_in[0];
  const int*   colind    = (const int*)d_in[1];
  // d_in[2] colptr, d_in[3] rowind: backward-only, unused in fwd
  const int*   permute   = (const int*)d_in[4];
  const float* feat      = (const float*)d_in[5];
  const float* pseudo    = (const float*)d_in[6];
  const float* fc_w      = (const float*)d_in[7];
  const float* mu        = (const float*)d_in[8];
  const float* inv_sigma = (const float*)d_in[9];
  const float* bias      = (const float*)d_in[10];
  float* out = (float*)d_out;
  float* nf  = (float*)d_ws;   // node_feat workspace: N*128 floats = 51.2 MB

  // Kernel A: 100000/16 = 6250 blocks
  gmm_fc_gemm<<<NN / 16, 256, 0, stream>>>(feat, fc_w, nf);
  // Kernel B: 100000/32 = 3125 blocks
  gmm_edge_scatter<<<NN / 32, 256, 0, stream>>>(
      rowptr, colind, permute, pseudo, mu, inv_sigma, bias, nf, out);
}

// Round 2
// 245.185 us; speedup vs baseline: 2.3680x; 2.3680x over previous
//
#include <hip/hip_runtime.h>

#define NN     100000
#define DEG    16
#define IN_F   128
#define OUT_F  32
#define KK     4
#define JDIM   (KK * OUT_F)   // 128

typedef __attribute__((ext_vector_type(8))) short short8;     // 8 bf16 = 4 VGPR
typedef __attribute__((ext_vector_type(4))) float floatx4;    // MFMA C/D

// fp32 -> bf16 bits, round-to-nearest-even (inputs are finite normals)
static __device__ __forceinline__ unsigned short f2bf(float f) {
  unsigned int u = __builtin_bit_cast(unsigned int, f);
  u += 0x7fffu + ((u >> 16) & 1u);
  return (unsigned short)(u >> 16);
}

// ---------------------------------------------------------------------------
// Kernel A (MFMA): nf_bf16[m][j] = sum_i feat[m][i] * fc_w[j][i]
// One wave per 16-node m-tile. 8 n-tiles x 4 K-steps = 32 MFMA per wave.
// A[m=lane&15][k=quad*8+e], B[k=quad*8+e][n=lane&15], C/D col=lane&15,
// row=quad*4+reg (guide m89-verified layouts). fc_w re-read per wave: L2-hot.
// ---------------------------------------------------------------------------
__global__ __launch_bounds__(256) void gmm_fc_mfma(
    const float* __restrict__ feat, const float* __restrict__ fc_w,
    unsigned short* __restrict__ nf)
{
  const int lane = threadIdx.x & 63;
  const int wv   = threadIdx.x >> 6;
  const int tile = blockIdx.x * 4 + wv;
  if (tile * 16 >= NN) return;             // NN % 16 == 0: tiles are full
  const int m0   = tile * 16;
  const int col  = lane & 15;
  const int quad = lane >> 4;

  floatx4 acc[8];
#pragma unroll
  for (int t = 0; t < 8; ++t) acc[t] = (floatx4){0.f, 0.f, 0.f, 0.f};

  const float* arow = feat + (size_t)(m0 + col) * IN_F + quad * 8;

#pragma unroll
  for (int s = 0; s < 4; ++s) {
    const float4 a0 = *(const float4*)(arow + s * 32);
    const float4 a1 = *(const float4*)(arow + s * 32 + 4);
    short8 av;
    av[0] = (short)f2bf(a0.x); av[1] = (short)f2bf(a0.y);
    av[2] = (short)f2bf(a0.z); av[3] = (short)f2bf(a0.w);
    av[4] = (short)f2bf(a1.x); av[5] = (short)f2bf(a1.y);
    av[6] = (short)f2bf(a1.z); av[7] = (short)f2bf(a1.w);
#pragma unroll
    for (int t = 0; t < 8; ++t) {
      const float* brow = fc_w + (size_t)(t * 16 + col) * IN_F + s * 32 + quad * 8;
      const float4 b0 = *(const float4*)(brow);
      const float4 b1 = *(const float4*)(brow + 4);
      short8 bv;
      bv[0] = (short)f2bf(b0.x); bv[1] = (short)f2bf(b0.y);
      bv[2] = (short)f2bf(b0.z); bv[3] = (short)f2bf(b0.w);
      bv[4] = (short)f2bf(b1.x); bv[5] = (short)f2bf(b1.y);
      bv[6] = (short)f2bf(b1.z); bv[7] = (short)f2bf(b1.w);
      acc[t] = __builtin_amdgcn_mfma_f32_16x16x32_bf16(av, bv, acc[t], 0, 0, 0);
    }
  }

  // C/D: element r of acc[t] -> node m0 + quad*4 + r, j = t*16 + col
#pragma unroll
  for (int t = 0; t < 8; ++t) {
#pragma unroll
    for (int r = 0; r < 4; ++r) {
      const int m = m0 + quad * 4 + r;
      nf[(size_t)m * JDIM + t * 16 + col] = f2bf(acc[t][r]);
    }
  }
}

// ---------------------------------------------------------------------------
// Kernel B: out[i][f] = bias[f] + sum_{e in row i} sum_k w[e,k]*nf[src_e][k*32+f]
// Block = 256 thr = 64 nodes x 4 lanes (8 features each, bf16x8 = uint4 loads,
// 4 lanes x 16B = 64B coalesced per (src,k)). 1024 edges staged in LDS.
// Edge read order rotated by local node id -> LDS bank-conflict-free.
// ---------------------------------------------------------------------------
__global__ __launch_bounds__(256) void gmm_edge_gather(
    const int* __restrict__ rowptr, const int* __restrict__ colind,
    const int* __restrict__ permute, const float* __restrict__ pseudo,
    const float* __restrict__ mu, const float* __restrict__ inv_sigma,
    const float* __restrict__ bias, const unsigned short* __restrict__ nf,
    float* __restrict__ out)
{
  __shared__ int   s_src[1024];      // 4 KB
  __shared__ float s_w[1024][4];     // 16 KB

  const int tid    = threadIdx.x;
  const int node0  = blockIdx.x * 64;
  const int nvalid = (NN - node0 < 64) ? (NN - node0) : 64;

  float mx[KK], my[KK], sx[KK], sy[KK];
#pragma unroll
  for (int k = 0; k < KK; ++k) {
    mx[k] = mu[k * 2 + 0];
    my[k] = mu[k * 2 + 1];
    sx[k] = inv_sigma[k * 2 + 0];
    sy[k] = inv_sigma[k * 2 + 1];
  }

  // stage 1024 edges (4 per thread): src id + 4 gaussian weights
#pragma unroll
  for (int r = 0; r < 4; ++r) {
    const int t  = tid + r * 256;
    const int nl = t >> 4;
    if (nl < nvalid) {
      const int e   = rowptr[node0 + nl] + (t & 15);
      const int pe  = permute[e];
      s_src[t] = colind[e];
      const float px = pseudo[(size_t)pe * 2 + 0];
      const float py = pseudo[(size_t)pe * 2 + 1];
#pragma unroll
      for (int k = 0; k < KK; ++k) {
        const float dx = (px - mx[k]) * sx[k];
        const float dy = (py - my[k]) * sy[k];
        s_w[t][k] = __expf(-0.5f * (dx * dx + dy * dy));
      }
    }
  }
  __syncthreads();

  const int nl = tid >> 2;    // local node 0..63
  const int f8 = tid & 3;     // features f8*8 .. f8*8+7
  if (nl >= nvalid) return;

  float acc[8];
  {
    const float4 b0 = *(const float4*)&bias[f8 * 8];
    const float4 b1 = *(const float4*)&bias[f8 * 8 + 4];
    acc[0] = b0.x; acc[1] = b0.y; acc[2] = b0.z; acc[3] = b0.w;
    acc[4] = b1.x; acc[5] = b1.y; acc[6] = b1.z; acc[7] = b1.w;
  }

  const int tbase = nl * 16;
#pragma unroll
  for (int i = 0; i < DEG; ++i) {
    const int e = (i + nl) & 15;          // rotate: conflict-free LDS reads
    const int t = tbase + e;
    const int src = s_src[t];
    const float4 w4 = *(const float4*)&s_w[t][0];
    const float wv[4] = {w4.x, w4.y, w4.z, w4.w};
    const unsigned short* row = nf + (size_t)src * JDIM + f8 * 8;
#pragma unroll
    for (int k = 0; k < KK; ++k) {
      const uint4 v = *(const uint4*)(row + k * 32);
      const float wk = wv[k];
      acc[0] += wk * __uint_as_float(v.x << 16);
      acc[1] += wk * __uint_as_float(v.x & 0xffff0000u);
      acc[2] += wk * __uint_as_float(v.y << 16);
      acc[3] += wk * __uint_as_float(v.y & 0xffff0000u);
      acc[4] += wk * __uint_as_float(v.z << 16);
      acc[5] += wk * __uint_as_float(v.z & 0xffff0000u);
      acc[6] += wk * __uint_as_float(v.w << 16);
      acc[7] += wk * __uint_as_float(v.w & 0xffff0000u);
    }
  }

  float4 o0 = {acc[0], acc[1], acc[2], acc[3]};
  float4 o1 = {acc[4], acc[5], acc[6], acc[7]};
  float* op = out + (size_t)(node0 + nl) * OUT_F + f8 * 8;
  *(float4*)(op)     = o0;
  *(float4*)(op + 4) = o1;
}

extern "C" void kernel_launch(void* const* d_in, const int* in_sizes, int n_in,
                              void* d_out, int out_size, void* d_ws, size_t ws_size,
                              hipStream_t stream) {
  const int*   rowptr    = (const int*)d_in[0];
  const int*   colind    = (const int*)d_in[1];
  // d_in[2] colptr, d_in[3] rowind: backward-only, unused in fwd
  const int*   permute   = (const int*)d_in[4];
  const float* feat      = (const float*)d_in[5];
  const float* pseudo    = (const float*)d_in[6];
  const float* fc_w      = (const float*)d_in[7];
  const float* mu        = (const float*)d_in[8];
  const float* inv_sigma = (const float*)d_in[9];
  const float* bias      = (const float*)d_in[10];
  float* out = (float*)d_out;
  unsigned short* nf = (unsigned short*)d_ws;   // bf16 node_feat: 25.6 MB

  // Kernel A: 6250 m-tiles, 4 waves/block -> 1563 blocks
  gmm_fc_mfma<<<(NN / 16 + 3) / 4, 256, 0, stream>>>(feat, fc_w, nf);
  // Kernel B: 64 nodes/block -> 1563 blocks
  gmm_edge_gather<<<(NN + 63) / 64, 256, 0, stream>>>(
      rowptr, colind, permute, pseudo, mu, inv_sigma, bias, nf, out);
}

// Round 3
// 198.534 us; speedup vs baseline: 2.9244x; 1.2350x over previous
//
#include <hip/hip_runtime.h>

#define NN     100000
#define DEG    16
#define IN_F   128
#define OUT_F  32
#define KK     4
#define JDIM   (KK * OUT_F)   // 128

typedef __attribute__((ext_vector_type(8))) short short8;     // 8 bf16 = 4 VGPR
typedef __attribute__((ext_vector_type(4))) short short4v;    // 4 bf16 = 8 B
typedef __attribute__((ext_vector_type(4))) float floatx4;    // MFMA C/D

// fp32 -> bf16 bits, round-to-nearest-even (inputs are finite normals)
static __device__ __forceinline__ unsigned short f2bf(float f) {
  unsigned int u = __builtin_bit_cast(unsigned int, f);
  u += 0x7fffu + ((u >> 16) & 1u);
  return (unsigned short)(u >> 16);
}

// ---------------------------------------------------------------------------
// Kernel P: fc_w (fp32, [128][128]) -> bf16 in MFMA A-fragment order.
// Slot g = (s*8+t)*64 + q*16 + c holds fc_w[t*16+c][s*32+q*8 .. +7], so in
// kernel A the wave's (s,t) fragment load is wcvt + ((s*8+t)*64 + lane)*8:
// fully coalesced 1 KB per instruction. 2048 threads, writes are g-linear.
// ---------------------------------------------------------------------------
__global__ __launch_bounds__(256) void gmm_cvt_w(
    const float* __restrict__ fc_w, unsigned short* __restrict__ wcvt)
{
  const int g = blockIdx.x * 256 + threadIdx.x;   // 0..2047
  const int c = g & 15, q = (g >> 4) & 3, t = (g >> 6) & 7, s = g >> 9;
  const float* src = fc_w + (size_t)(t * 16 + c) * IN_F + s * 32 + q * 8;
  const float4 f0 = *(const float4*)src;
  const float4 f1 = *(const float4*)(src + 4);
  short8 v;
  v[0] = (short)f2bf(f0.x); v[1] = (short)f2bf(f0.y);
  v[2] = (short)f2bf(f0.z); v[3] = (short)f2bf(f0.w);
  v[4] = (short)f2bf(f1.x); v[5] = (short)f2bf(f1.y);
  v[6] = (short)f2bf(f1.z); v[7] = (short)f2bf(f1.w);
  *(short8*)(wcvt + (size_t)g * 8) = v;
}

// ---------------------------------------------------------------------------
// Kernel A (MFMA): nf_bf16[m][j] = sum_i feat[m][i] * fc_w[j][i]
// One wave per 16-node m-tile; A = W tile (M=j), B = feat^T (N=node).
// A-frag: coalesced short8 from wcvt (L2-hot, no conversion).
// B-frag: feat row (8 contiguous fp32 -> bf16, 32 cvt/lane total).
// D: row = j-local = q*4+r, col = node -> 4 contiguous j per reg-quad:
// epilogue packs 4 bf16 -> 8 B stores.
// ---------------------------------------------------------------------------
__global__ __launch_bounds__(256) void gmm_fc_mfma(
    const float* __restrict__ feat, const unsigned short* __restrict__ wcvt,
    unsigned short* __restrict__ nf)
{
  const int lane = threadIdx.x & 63;
  const int wv   = threadIdx.x >> 6;
  const int tile = blockIdx.x * 4 + wv;
  if (tile * 16 >= NN) return;             // NN % 16 == 0: tiles are full
  const int m0 = tile * 16;
  const int c  = lane & 15;
  const int q  = lane >> 4;

  floatx4 acc[8];
#pragma unroll
  for (int t = 0; t < 8; ++t) acc[t] = (floatx4){0.f, 0.f, 0.f, 0.f};

  const float*  frow  = feat + (size_t)(m0 + c) * IN_F + q * 8;
  const short8* wbase = (const short8*)wcvt;

#pragma unroll
  for (int s = 0; s < 4; ++s) {
    const float4 b0 = *(const float4*)(frow + s * 32);
    const float4 b1 = *(const float4*)(frow + s * 32 + 4);
    short8 bv;
    bv[0] = (short)f2bf(b0.x); bv[1] = (short)f2bf(b0.y);
    bv[2] = (short)f2bf(b0.z); bv[3] = (short)f2bf(b0.w);
    bv[4] = (short)f2bf(b1.x); bv[5] = (short)f2bf(b1.y);
    bv[6] = (short)f2bf(b1.z); bv[7] = (short)f2bf(b1.w);
#pragma unroll
    for (int t = 0; t < 8; ++t) {
      const short8 av = wbase[(s * 8 + t) * 64 + lane];
      acc[t] = __builtin_amdgcn_mfma_f32_16x16x32_bf16(av, bv, acc[t], 0, 0, 0);
    }
  }

  // D element r of acc[t]: node = m0+c, j = t*16 + q*4 + r (contiguous in r)
#pragma unroll
  for (int t = 0; t < 8; ++t) {
    short4v p;
    p[0] = (short)f2bf(acc[t][0]); p[1] = (short)f2bf(acc[t][1]);
    p[2] = (short)f2bf(acc[t][2]); p[3] = (short)f2bf(acc[t][3]);
    *(short4v*)(nf + (size_t)(m0 + c) * JDIM + t * 16 + q * 4) = p;
  }
}

// ---------------------------------------------------------------------------
// Kernel B: out[i][f] = bias[f] + sum_{e in row i} sum_k w[e,k]*nf[src_e][k*32+f]
// Block = 256 thr = 64 nodes x 4 lanes (8 features each, bf16x8 = uint4 loads,
// 4 lanes x 16B = 64B coalesced per (src,k)). 1024 edges staged in LDS.
// Edge read order rotated by local node id -> LDS bank-conflict-free.
// ---------------------------------------------------------------------------
__global__ __launch_bounds__(256) void gmm_edge_gather(
    const int* __restrict__ rowptr, const int* __restrict__ colind,
    const int* __restrict__ permute, const float* __restrict__ pseudo,
    const float* __restrict__ mu, const float* __restrict__ inv_sigma,
    const float* __restrict__ bias, const unsigned short* __restrict__ nf,
    float* __restrict__ out)
{
  __shared__ int   s_src[1024];      // 4 KB
  __shared__ float s_w[1024][4];     // 16 KB

  const int tid    = threadIdx.x;
  const int node0  = blockIdx.x * 64;
  const int nvalid = (NN - node0 < 64) ? (NN - node0) : 64;

  float mx[KK], my[KK], sx[KK], sy[KK];
#pragma unroll
  for (int k = 0; k < KK; ++k) {
    mx[k] = mu[k * 2 + 0];
    my[k] = mu[k * 2 + 1];
    sx[k] = inv_sigma[k * 2 + 0];
    sy[k] = inv_sigma[k * 2 + 1];
  }

  // stage 1024 edges (4 per thread): src id + 4 gaussian weights
#pragma unroll
  for (int r = 0; r < 4; ++r) {
    const int t  = tid + r * 256;
    const int nl = t >> 4;
    if (nl < nvalid) {
      const int e   = rowptr[node0 + nl] + (t & 15);
      const int pe  = permute[e];
      s_src[t] = colind[e];
      const float px = pseudo[(size_t)pe * 2 + 0];
      const float py = pseudo[(size_t)pe * 2 + 1];
#pragma unroll
      for (int k = 0; k < KK; ++k) {
        const float dx = (px - mx[k]) * sx[k];
        const float dy = (py - my[k]) * sy[k];
        s_w[t][k] = __expf(-0.5f * (dx * dx + dy * dy));
      }
    }
  }
  __syncthreads();

  const int nl = tid >> 2;    // local node 0..63
  const int f8 = tid & 3;     // features f8*8 .. f8*8+7
  if (nl >= nvalid) return;

  float acc[8];
  {
    const float4 b0 = *(const float4*)&bias[f8 * 8];
    const float4 b1 = *(const float4*)&bias[f8 * 8 + 4];
    acc[0] = b0.x; acc[1] = b0.y; acc[2] = b0.z; acc[3] = b0.w;
    acc[4] = b1.x; acc[5] = b1.y; acc[6] = b1.z; acc[7] = b1.w;
  }

  const int tbase = nl * 16;
#pragma unroll
  for (int i = 0; i < DEG; ++i) {
    const int e = (i + nl) & 15;          // rotate: conflict-free LDS reads
    const int t = tbase + e;
    const int src = s_src[t];
    const float4 w4 = *(const float4*)&s_w[t][0];
    const float wv[4] = {w4.x, w4.y, w4.z, w4.w};
    const unsigned short* row = nf + (size_t)src * JDIM + f8 * 8;
#pragma unroll
    for (int k = 0; k < KK; ++k) {
      const uint4 v = *(const uint4*)(row + k * 32);
      const float wk = wv[k];
      acc[0] += wk * __uint_as_float(v.x << 16);
      acc[1] += wk * __uint_as_float(v.x & 0xffff0000u);
      acc[2] += wk * __uint_as_float(v.y << 16);
      acc[3] += wk * __uint_as_float(v.y & 0xffff0000u);
      acc[4] += wk * __uint_as_float(v.z << 16);
      acc[5] += wk * __uint_as_float(v.z & 0xffff0000u);
      acc[6] += wk * __uint_as_float(v.w << 16);
      acc[7] += wk * __uint_as_float(v.w & 0xffff0000u);
    }
  }

  float4 o0 = {acc[0], acc[1], acc[2], acc[3]};
  float4 o1 = {acc[4], acc[5], acc[6], acc[7]};
  float* op = out + (size_t)(node0 + nl) * OUT_F + f8 * 8;
  *(float4*)(op)     = o0;
  *(float4*)(op + 4) = o1;
}

extern "C" void kernel_launch(void* const* d_in, const int* in_sizes, int n_in,
                              void* d_out, int out_size, void* d_ws, size_t ws_size,
                              hipStream_t stream) {
  const int*   rowptr    = (const int*)d_in[0];
  const int*   colind    = (const int*)d_in[1];
  // d_in[2] colptr, d_in[3] rowind: backward-only, unused in fwd
  const int*   permute   = (const int*)d_in[4];
  const float* feat      = (const float*)d_in[5];
  const float* pseudo    = (const float*)d_in[6];
  const float* fc_w      = (const float*)d_in[7];
  const float* mu        = (const float*)d_in[8];
  const float* inv_sigma = (const float*)d_in[9];
  const float* bias      = (const float*)d_in[10];
  float* out = (float*)d_out;

  unsigned short* nf   = (unsigned short*)d_ws;                      // 25.6 MB
  unsigned short* wcvt = (unsigned short*)((char*)d_ws + (26u << 20)); // 32 KB

  // P: fc_w fp32 -> bf16, fragment order (2048 threads)
  gmm_cvt_w<<<8, 256, 0, stream>>>(fc_w, wcvt);
  // A: 6250 m-tiles, 4 waves/block -> 1563 blocks
  gmm_fc_mfma<<<(NN / 16 + 3) / 4, 256, 0, stream>>>(feat, wcvt, nf);
  // B: 64 nodes/block -> 1563 blocks
  gmm_edge_gather<<<(NN + 63) / 64, 256, 0, stream>>>(
      rowptr, colind, permute, pseudo, mu, inv_sigma, bias, nf, out);
}